// Round 3
// baseline (588.408 us; speedup 1.0000x reference)
//
#include <hip/hip_runtime.h>
#include <hip/hip_bf16.h>

using bf16 = __hip_bfloat16;

typedef __attribute__((ext_vector_type(8))) short short8;   // 8 bf16 = 16B
typedef __attribute__((ext_vector_type(4))) short shortx4;  // 4 bf16 = 8B
typedef __attribute__((ext_vector_type(4))) float f32x4;    // 16B

#define MFMA_BF16(a, b, c) __builtin_amdgcn_mfma_f32_16x16x32_bf16((a), (b), (c), 0, 0, 0)

__device__ __forceinline__ short bf16_hi(float x, float& hf) {
    bf16 h = __float2bfloat16(x);
    hf = __bfloat162float(h);
    return *(short*)&h;
}

// ---------------------------------------------------------------------------
// Weight transpose (fp32): in[K][N] -> out[N][K]
// ---------------------------------------------------------------------------
__global__ void transpose_f32(const float* __restrict__ in, float* __restrict__ out,
                              int K, int N) {
    __shared__ float t[32][33];
    const int n0 = blockIdx.x * 32, k0 = blockIdx.y * 32;
    const int tx = threadIdx.x, ty = threadIdx.y;  // (32, 8)
#pragma unroll
    for (int i = 0; i < 4; ++i)
        t[ty + i * 8][tx] = in[(size_t)(k0 + ty + i * 8) * N + n0 + tx];
    __syncthreads();
#pragma unroll
    for (int i = 0; i < 4; ++i)
        out[(size_t)(n0 + ty + i * 8) * K + k0 + tx] = t[tx][ty + i * 8];
}

// ---------------------------------------------------------------------------
// Tiled MFMA GEMM on fp32 inputs: C[M][N] = A[M][K] @ Bt[N][K]^T + bias[N]
// fp32 global -> bf16 (hi, and lo if M_SPLIT) staged in LDS.
//   M_PLAIN: 1-MFMA (hi*hi), out0 = fp32 row-major
//   M_SPLIT: 3-MFMA hi/lo (fp32-accurate), out0/out1 = bf16 hi/lo of C
//   M_VT   : 1-MFMA, out0 = bf16 transposed per batch [(b*N+n)*256 + m%256]
// Tile 128x128x32, 4 waves, 4x4 MFMA tiles per wave.
// ---------------------------------------------------------------------------
constexpr int BM = 128, BN = 128, BK = 32, LDP = 40;
enum { M_PLAIN = 0, M_SPLIT = 1, M_VT = 2 };

template <int MODE, bool A_BF16>
__global__ __launch_bounds__(256) void gemm_bt(
    const void* __restrict__ Av, const float* __restrict__ Bt,
    const float* __restrict__ bias, void* __restrict__ out0,
    void* __restrict__ out1, int M, int N, int K) {
    __shared__ bf16 Ash[BM * LDP];
    __shared__ bf16 Bsh[BN * LDP];
    __shared__ bf16 Asl[(MODE == M_SPLIT) ? BM * LDP : 1];
    __shared__ bf16 Bsl[(MODE == M_SPLIT) ? BN * LDP : 1];
    __shared__ bf16 Ts[(MODE == M_VT) ? 128 * 136 : 1];

    const int tid = threadIdx.x;
    const int wave = tid >> 6, lane = tid & 63;
    const int quad = lane >> 4, l15 = lane & 15;
    const int wr = wave >> 1, wc = wave & 1;
    const int m0 = blockIdx.y * BM, n0 = blockIdx.x * BN;

    f32x4 acc[4][4] = {};

    for (int k0 = 0; k0 < K; k0 += BK) {
        // ---- stage A tile ----
        if constexpr (A_BF16) {
#pragma unroll
            for (int it = 0; it < 2; ++it) {
                const int c = tid + 256 * it;
                const int row = c >> 2, col = (c & 3) * 8;
                *(short8*)(&Ash[row * LDP + col]) =
                    *(const short8*)((const bf16*)Av + (size_t)(m0 + row) * K + k0 + col);
            }
        } else {
#pragma unroll
            for (int it = 0; it < 4; ++it) {
                const int idx = tid + 256 * it;
                const int row = idx >> 3, cg = (idx & 7) * 4;
                const f32x4 x =
                    *(const f32x4*)((const float*)Av + (size_t)(m0 + row) * K + k0 + cg);
                shortx4 h, l;
#pragma unroll
                for (int j = 0; j < 4; ++j) {
                    float hf;
                    h[j] = bf16_hi(x[j], hf);
                    if constexpr (MODE == M_SPLIT) {
                        float lf;
                        l[j] = bf16_hi(x[j] - hf, lf);
                    }
                }
                *(shortx4*)(&Ash[row * LDP + cg]) = h;
                if constexpr (MODE == M_SPLIT) *(shortx4*)(&Asl[row * LDP + cg]) = l;
            }
        }
        // ---- stage B tile (always fp32 source) ----
#pragma unroll
        for (int it = 0; it < 4; ++it) {
            const int idx = tid + 256 * it;
            const int row = idx >> 3, cg = (idx & 7) * 4;
            const f32x4 x = *(const f32x4*)(Bt + (size_t)(n0 + row) * K + k0 + cg);
            shortx4 h, l;
#pragma unroll
            for (int j = 0; j < 4; ++j) {
                float hf;
                h[j] = bf16_hi(x[j], hf);
                if constexpr (MODE == M_SPLIT) {
                    float lf;
                    l[j] = bf16_hi(x[j] - hf, lf);
                }
            }
            *(shortx4*)(&Bsh[row * LDP + cg]) = h;
            if constexpr (MODE == M_SPLIT) *(shortx4*)(&Bsl[row * LDP + cg]) = l;
        }
        __syncthreads();

        short8 ah[4], bh[4];
#pragma unroll
        for (int t = 0; t < 4; ++t) {
            ah[t] = *(const short8*)(&Ash[(wr * 64 + t * 16 + l15) * LDP + quad * 8]);
            bh[t] = *(const short8*)(&Bsh[(wc * 64 + t * 16 + l15) * LDP + quad * 8]);
        }
        if constexpr (MODE == M_SPLIT) {
            short8 al[4], bl[4];
#pragma unroll
            for (int t = 0; t < 4; ++t) {
                al[t] = *(const short8*)(&Asl[(wr * 64 + t * 16 + l15) * LDP + quad * 8]);
                bl[t] = *(const short8*)(&Bsl[(wc * 64 + t * 16 + l15) * LDP + quad * 8]);
            }
#pragma unroll
            for (int ti = 0; ti < 4; ++ti)
#pragma unroll
                for (int tj = 0; tj < 4; ++tj) {
                    acc[ti][tj] = MFMA_BF16(al[ti], bh[tj], acc[ti][tj]);
                    acc[ti][tj] = MFMA_BF16(ah[ti], bl[tj], acc[ti][tj]);
                    acc[ti][tj] = MFMA_BF16(ah[ti], bh[tj], acc[ti][tj]);
                }
        } else {
#pragma unroll
            for (int ti = 0; ti < 4; ++ti)
#pragma unroll
                for (int tj = 0; tj < 4; ++tj)
                    acc[ti][tj] = MFMA_BF16(ah[ti], bh[tj], acc[ti][tj]);
        }
        __syncthreads();
    }

    float bv[4];
#pragma unroll
    for (int tj = 0; tj < 4; ++tj) bv[tj] = bias[n0 + wc * 64 + tj * 16 + l15];

    if constexpr (MODE == M_VT) {
        // C tile into LDS as [n_local][m_local], then store transposed (bf16)
#pragma unroll
        for (int ti = 0; ti < 4; ++ti)
#pragma unroll
            for (int tj = 0; tj < 4; ++tj)
#pragma unroll
                for (int i = 0; i < 4; ++i) {
                    const int ml = wr * 64 + ti * 16 + quad * 4 + i;
                    const int nl = wc * 64 + tj * 16 + l15;
                    Ts[nl * 136 + ml] = __float2bfloat16(acc[ti][tj][i] + bv[tj]);
                }
        __syncthreads();
        const int bIdx = m0 >> 8, tok0 = m0 & 255;
        const int nl = tid >> 1, half = tid & 1;
        bf16* dst = (bf16*)out0 + ((size_t)bIdx * N + n0 + nl) * 256 + tok0 + half * 64;
        const bf16* src = &Ts[nl * 136 + half * 64];
#pragma unroll
        for (int j = 0; j < 8; ++j) *(short8*)(dst + j * 8) = *(const short8*)(src + j * 8);
    } else {
#pragma unroll
        for (int ti = 0; ti < 4; ++ti)
#pragma unroll
            for (int tj = 0; tj < 4; ++tj)
#pragma unroll
                for (int i = 0; i < 4; ++i) {
                    const size_t row = m0 + wr * 64 + ti * 16 + quad * 4 + i;
                    const size_t col = n0 + wc * 64 + tj * 16 + l15;
                    const float v = acc[ti][tj][i] + bv[tj];
                    if constexpr (MODE == M_PLAIN) {
                        ((float*)out0)[row * N + col] = v;
                    } else {
                        float hf;
                        const short hs = bf16_hi(v, hf);
                        ((short*)out0)[row * N + col] = hs;
                        float lf;
                        ((short*)out1)[row * N + col] = bf16_hi(v - hf, lf);
                    }
                }
    }
}

// ---------------------------------------------------------------------------
// Attention: block = (batch b, 64 q-rows); 4 waves x 16 rows.
// s = q@k^T via hi/lo MFMA (fp32 logits), softmax, post-softmax mask,
// beta -> fp32 d_out + bf16 LDS, o_mid = beta@v via MFMA (vT contiguous).
// ---------------------------------------------------------------------------
__global__ __launch_bounds__(256) void attn_kernel(
    const bf16* __restrict__ qh, const bf16* __restrict__ ql,
    const bf16* __restrict__ kh, const bf16* __restrict__ kl,
    const bf16* __restrict__ vT, const float* __restrict__ masks,
    float* __restrict__ beta_out, bf16* __restrict__ o_mid) {
    __shared__ bf16 betaS[64 * 264];
    const int b = blockIdx.y, qt = blockIdx.x;
    const int tid = threadIdx.x, wave = tid >> 6, lane = tid & 63;
    const int quad = lane >> 4, l15 = lane & 15;
    const int rowbase = qt * 64, mw = wave * 16;

    f32x4 acc[16] = {};
    const size_t qoff = ((size_t)(b * 256 + rowbase + mw + l15)) * 512;
    const size_t koff0 = ((size_t)b * 256) * 512;
    for (int k0 = 0; k0 < 512; k0 += 32) {
        const short8 aH = *(const short8*)(qh + qoff + k0 + quad * 8);
        const short8 aL = *(const short8*)(ql + qoff + k0 + quad * 8);
#pragma unroll
        for (int nt = 0; nt < 16; ++nt) {
            const size_t ko = koff0 + (size_t)(nt * 16 + l15) * 512 + k0 + quad * 8;
            const short8 bH = *(const short8*)(kh + ko);
            const short8 bL = *(const short8*)(kl + ko);
            acc[nt] = MFMA_BF16(aH, bH, acc[nt]);
            acc[nt] = MFMA_BF16(aH, bL, acc[nt]);
            acc[nt] = MFMA_BF16(aL, bH, acc[nt]);
        }
    }

    float inv[4], mx[4];
#pragma unroll
    for (int i = 0; i < 4; ++i) {
        float m = -1e30f;
#pragma unroll
        for (int nt = 0; nt < 16; ++nt) m = fmaxf(m, acc[nt][i]);
#pragma unroll
        for (int s = 1; s < 16; s <<= 1) m = fmaxf(m, __shfl_xor(m, s));
        mx[i] = m;
    }
#pragma unroll
    for (int i = 0; i < 4; ++i) {
        float s = 0.f;
#pragma unroll
        for (int nt = 0; nt < 16; ++nt) {
            const float e = expf(acc[nt][i] - mx[i]);
            acc[nt][i] = e;
            s += e;
        }
#pragma unroll
        for (int sh = 1; sh < 16; sh <<= 1) s += __shfl_xor(s, sh);
        inv[i] = 1.0f / s;
    }

#pragma unroll
    for (int nt = 0; nt < 16; ++nt) {
        const float mv = masks[b * 256 + nt * 16 + l15];
#pragma unroll
        for (int i = 0; i < 4; ++i) {
            const float bvv = acc[nt][i] * inv[i] * mv;
            const int rloc = mw + quad * 4 + i;
            beta_out[((size_t)(b * 256 + rowbase + rloc)) * 256 + nt * 16 + l15] = bvv;
            betaS[rloc * 264 + nt * 16 + l15] = __float2bfloat16(bvv);
        }
    }
    __syncthreads();

#pragma unroll 1
    for (int cg = 0; cg < 8; ++cg) {
        f32x4 oacc[8] = {};
#pragma unroll
        for (int k0 = 0; k0 < 256; k0 += 32) {
            const short8 aB = *(const short8*)(&betaS[(mw + l15) * 264 + k0 + quad * 8]);
#pragma unroll
            for (int cc = 0; cc < 8; ++cc) {
                const int ct = cg * 8 + cc;
                const short8 bV = *(const short8*)(
                    vT + ((size_t)(b * 1024 + ct * 16 + l15)) * 256 + k0 + quad * 8);
                oacc[cc] = MFMA_BF16(aB, bV, oacc[cc]);
            }
        }
#pragma unroll
        for (int cc = 0; cc < 8; ++cc)
#pragma unroll
            for (int i = 0; i < 4; ++i) {
                const int tok = rowbase + mw + quad * 4 + i;
                const int c = (cg * 8 + cc) * 16 + l15;
                o_mid[((size_t)(b * 256 + tok)) * 1024 + c] = __float2bfloat16(oacc[cc][i]);
            }
    }
}

// ---------------------------------------------------------------------------
extern "C" void kernel_launch(void* const* d_in, const int* in_sizes, int n_in,
                              void* d_out, int out_size, void* d_ws, size_t ws_size,
                              hipStream_t stream) {
    const float* x1 = (const float*)d_in[0];
    const float* x2 = (const float*)d_in[1];
    const float* masks = (const float*)d_in[2];
    const float* Wq = (const float*)d_in[3];
    const float* bq = (const float*)d_in[4];
    const float* Wk = (const float*)d_in[5];
    const float* bk = (const float*)d_in[6];
    const float* Wv = (const float*)d_in[7];
    const float* bv = (const float*)d_in[8];
    const float* Wo = (const float*)d_in[9];
    const float* bo = (const float*)d_in[10];

    char* ws = (char*)d_ws;
    float* WqT = (float*)(ws + 0);                //  512x1024 f32
    float* WkT = (float*)(ws + 2097152);          //  512x 768 f32
    float* WvT = (float*)(ws + 3670016);          // 1024x 768 f32
    float* WoT = (float*)(ws + 6815744);          // 1024x1024 f32
    bf16* q_hi = (bf16*)(ws + 11010048);          // 16384x512 bf16
    bf16* q_lo = (bf16*)(ws + 27787264);
    bf16* k_hi = (bf16*)(ws + 44564480);
    bf16* k_lo = (bf16*)(ws + 61341696);
    bf16* vT   = (bf16*)(ws + 78118912);          // [b][c][t] bf16
    bf16* o_mid = (bf16*)(ws + 111673344);        // 16384x1024 bf16
    // total ws use: 145,227,776 bytes

    float* out_o = (float*)d_out;
    float* out_beta = out_o + (size_t)16384 * 1024;

    const dim3 tb(32, 8);
    transpose_f32<<<dim3(16, 32), tb, 0, stream>>>(Wq, WqT, 1024, 512);
    transpose_f32<<<dim3(16, 24), tb, 0, stream>>>(Wk, WkT, 768, 512);
    transpose_f32<<<dim3(32, 24), tb, 0, stream>>>(Wv, WvT, 768, 1024);
    transpose_f32<<<dim3(32, 32), tb, 0, stream>>>(Wo, WoT, 1024, 1024);

    gemm_bt<M_SPLIT, false><<<dim3(4, 128), 256, 0, stream>>>(
        x1, WqT, bq, q_hi, q_lo, 16384, 512, 1024);
    gemm_bt<M_SPLIT, false><<<dim3(4, 128), 256, 0, stream>>>(
        x2, WkT, bk, k_hi, k_lo, 16384, 512, 768);
    gemm_bt<M_VT, false><<<dim3(8, 128), 256, 0, stream>>>(
        x2, WvT, bv, vT, nullptr, 16384, 1024, 768);

    attn_kernel<<<dim3(4, 64), 256, 0, stream>>>(q_hi, q_lo, k_hi, k_lo, vT, masks,
                                                 out_beta, o_mid);

    gemm_bt<M_PLAIN, true><<<dim3(8, 128), 256, 0, stream>>>(
        o_mid, WoT, bo, out_o, nullptr, 16384, 1024, 1024);
}

// Round 4
// 510.025 us; speedup vs baseline: 1.1537x; 1.1537x over previous
//
#include <hip/hip_runtime.h>
#include <hip/hip_bf16.h>

using bf16 = __hip_bfloat16;

typedef __attribute__((ext_vector_type(8))) short short8;   // 8 bf16 = 16B
typedef __attribute__((ext_vector_type(4))) short shortx4;  // 4 bf16 = 8B
typedef __attribute__((ext_vector_type(4))) float f32x4;    // 16B

#define MFMA_BF16(a, b, c) __builtin_amdgcn_mfma_f32_16x16x32_bf16((a), (b), (c), 0, 0, 0)

// async global->LDS, 16B per lane; LDS dest = wave-uniform base + lane*16
__device__ __forceinline__ void lds_load16(const void* g, void* l) {
    __builtin_amdgcn_global_load_lds(
        (const __attribute__((address_space(1))) void*)g,
        (__attribute__((address_space(3))) void*)l, 16, 0, 0);
}

// stage 128x32 bf16 tile (row-major src, ld elems) -> LDS stride 32, 256-thr block
__device__ __forceinline__ void stage_async_128(const bf16* src, int ld, bf16* tile,
                                                int wave, int lane) {
    const int r = lane >> 2, c = (lane & 3) * 8;
#pragma unroll
    for (int p = 0; p < 2; ++p) {
        const int row = p * 64 + wave * 16;
        lds_load16(src + (size_t)(row + r) * ld + c, tile + row * 32);
    }
}
// stage 256x32 bf16 tile with 512-thr block (8 waves)
__device__ __forceinline__ void stage_async_256_w8(const bf16* src, int ld, bf16* tile,
                                                   int wave, int lane) {
    const int r = lane >> 2, c = (lane & 3) * 8;
#pragma unroll
    for (int p = 0; p < 2; ++p) {
        const int row = p * 128 + wave * 16;
        lds_load16(src + (size_t)(row + r) * ld + c, tile + row * 32);
    }
}
// stage 128x32 fp32 tile with hi(/lo) bf16 conversion -> LDS stride 40
template <bool SPLIT>
__device__ __forceinline__ void stage_conv_128(const float* src, int ld, bf16* th,
                                               bf16* tl, int tid) {
#pragma unroll
    for (int it = 0; it < 4; ++it) {
        const int vid = tid + 256 * it;
        const int row = vid >> 3, col = (vid & 7) * 4;
        const f32x4 x = *(const f32x4*)(src + (size_t)row * ld + col);
        shortx4 h, l;
#pragma unroll
        for (int j = 0; j < 4; ++j) {
            bf16 hb = __float2bfloat16(x[j]);
            h[j] = *(short*)&hb;
            if constexpr (SPLIT) {
                bf16 lb = __float2bfloat16(x[j] - __bfloat162float(hb));
                l[j] = *(short*)&lb;
            }
        }
        *(shortx4*)(&th[row * 40 + col]) = h;
        if constexpr (SPLIT) *(shortx4*)(&tl[row * 40 + col]) = l;
    }
}

// ---------------------------------------------------------------------------
// Weight transpose fp32 in[K][N] -> bf16 hi(/lo) out[N][K]
// ---------------------------------------------------------------------------
template <bool SPLIT>
__global__ void transpose_split(const float* __restrict__ in, bf16* __restrict__ outh,
                                bf16* __restrict__ outl, int K, int N) {
    __shared__ float t[32][33];
    const int n0 = blockIdx.x * 32, k0 = blockIdx.y * 32;
    const int tx = threadIdx.x, ty = threadIdx.y;  // (32, 8)
#pragma unroll
    for (int i = 0; i < 4; ++i)
        t[ty + i * 8][tx] = in[(size_t)(k0 + ty + i * 8) * N + n0 + tx];
    __syncthreads();
#pragma unroll
    for (int i = 0; i < 4; ++i) {
        const float x = t[tx][ty + i * 8];
        const bf16 hb = __float2bfloat16(x);
        const size_t idx = (size_t)(n0 + ty + i * 8) * K + k0 + tx;
        outh[idx] = hb;
        if constexpr (SPLIT) outl[idx] = __float2bfloat16(x - __bfloat162float(hb));
    }
}

// ---------------------------------------------------------------------------
// Unified 128x128x32 MFMA GEMM, C = A @ Bt^T (+bias). 4 waves, 4x4 tiles/wave.
//  G_SPLIT3: A fp32 (conv hi/lo), B bf16 hi/lo async; 3-MFMA; out hi/lo bf16.
//  G_VT    : A fp32 (conv hi), B bf16 async; out bf16 transposed per batch.
//  G_F32   : A bf16 async, B bf16 async; out fp32 + bias.
//  G_PV    : batched (z): A bf16 async, B bf16 async; out bf16, no bias.
// ---------------------------------------------------------------------------
enum { G_SPLIT3 = 0, G_VT = 1, G_F32 = 2, G_PV = 3 };

template <int MODE>
__global__ __launch_bounds__(256) void gemm2(
    const void* __restrict__ Av, const bf16* __restrict__ Bth,
    const bf16* __restrict__ Btl, const float* __restrict__ bias,
    void* __restrict__ out0, void* __restrict__ out1, int N, int K) {
    constexpr bool ASPLIT = (MODE == G_SPLIT3);
    constexpr bool ACONV = (MODE == G_SPLIT3 || MODE == G_VT);
    constexpr int LDA = ACONV ? 40 : 32;
    __shared__ bf16 AsH[128 * LDA];
    __shared__ bf16 AsL[ASPLIT ? 128 * 40 : 1];
    __shared__ bf16 BsH[128 * 32];
    __shared__ bf16 BsL[ASPLIT ? 128 * 32 : 1];
    __shared__ bf16 Ts[(MODE == G_VT) ? 128 * 136 : 1];

    const int tid = threadIdx.x, wave = tid >> 6, lane = tid & 63;
    const int quad = lane >> 4, l15 = lane & 15;
    const int wr = wave >> 1, wc = wave & 1;
    const int m0 = blockIdx.y * 128, n0 = blockIdx.x * 128;
    const int z = blockIdx.z;

    const float* Af = (const float*)Av;
    const bf16* Ab = (const bf16*)Av;
    const bf16* Bh = Bth;
    if constexpr (MODE == G_PV) {
        Ab += (size_t)z * 256 * 256;      // beta batch
        Bh += (size_t)z * 1024 * 256;     // vT batch
    }

    f32x4 acc[4][4] = {};
    for (int k0 = 0; k0 < K; k0 += 32) {
        if constexpr (ACONV)
            stage_conv_128<ASPLIT>(Af + (size_t)m0 * K + k0, K, AsH, AsL, tid);
        else
            stage_async_128(Ab + (size_t)m0 * K + k0, K, AsH, wave, lane);
        stage_async_128(Bh + (size_t)n0 * K + k0, K, BsH, wave, lane);
        if constexpr (ASPLIT)
            stage_async_128(Btl + (size_t)n0 * K + k0, K, BsL, wave, lane);
        __syncthreads();

        short8 ah[4], bh[4];
#pragma unroll
        for (int t = 0; t < 4; ++t) {
            ah[t] = *(const short8*)(&AsH[(wr * 64 + t * 16 + l15) * LDA + quad * 8]);
            bh[t] = *(const short8*)(&BsH[(wc * 64 + t * 16 + l15) * 32 + quad * 8]);
        }
        if constexpr (ASPLIT) {
            short8 al[4], bl[4];
#pragma unroll
            for (int t = 0; t < 4; ++t) {
                al[t] = *(const short8*)(&AsL[(wr * 64 + t * 16 + l15) * 40 + quad * 8]);
                bl[t] = *(const short8*)(&BsL[(wc * 64 + t * 16 + l15) * 32 + quad * 8]);
            }
#pragma unroll
            for (int ti = 0; ti < 4; ++ti)
#pragma unroll
                for (int tj = 0; tj < 4; ++tj) {
                    acc[ti][tj] = MFMA_BF16(al[ti], bh[tj], acc[ti][tj]);
                    acc[ti][tj] = MFMA_BF16(ah[ti], bl[tj], acc[ti][tj]);
                    acc[ti][tj] = MFMA_BF16(ah[ti], bh[tj], acc[ti][tj]);
                }
        } else {
#pragma unroll
            for (int ti = 0; ti < 4; ++ti)
#pragma unroll
                for (int tj = 0; tj < 4; ++tj)
                    acc[ti][tj] = MFMA_BF16(ah[ti], bh[tj], acc[ti][tj]);
        }
        __syncthreads();
    }

    float bv4[4] = {0.f, 0.f, 0.f, 0.f};
    if constexpr (MODE != G_PV) {
#pragma unroll
        for (int tj = 0; tj < 4; ++tj) bv4[tj] = bias[n0 + wc * 64 + tj * 16 + l15];
    }

    if constexpr (MODE == G_VT) {
#pragma unroll
        for (int ti = 0; ti < 4; ++ti)
#pragma unroll
            for (int tj = 0; tj < 4; ++tj)
#pragma unroll
                for (int i = 0; i < 4; ++i) {
                    const int ml = wr * 64 + ti * 16 + quad * 4 + i;
                    const int nl = wc * 64 + tj * 16 + l15;
                    Ts[nl * 136 + ml] = __float2bfloat16(acc[ti][tj][i] + bv4[tj]);
                }
        __syncthreads();
        const int bIdx = m0 >> 8, tok0 = m0 & 255;
        const int nl = tid >> 1, half = tid & 1;
        bf16* dst = (bf16*)out0 + ((size_t)bIdx * N + n0 + nl) * 256 + tok0 + half * 64;
        const bf16* src = &Ts[nl * 136 + half * 64];
#pragma unroll
        for (int j = 0; j < 8; ++j)
            *(short8*)(dst + j * 8) = *(const short8*)(src + j * 8);
    } else {
#pragma unroll
        for (int ti = 0; ti < 4; ++ti)
#pragma unroll
            for (int tj = 0; tj < 4; ++tj)
#pragma unroll
                for (int i = 0; i < 4; ++i) {
                    const size_t row = m0 + wr * 64 + ti * 16 + quad * 4 + i;
                    const size_t col = n0 + wc * 64 + tj * 16 + l15;
                    const float v = acc[ti][tj][i] + bv4[tj];
                    if constexpr (MODE == G_F32) {
                        ((float*)out0)[row * N + col] = v;
                    } else if constexpr (MODE == G_PV) {
                        ((bf16*)out0)[((size_t)z * 256 + row) * N + col] =
                            __float2bfloat16(v);
                    } else {  // G_SPLIT3: hi/lo outputs
                        const bf16 hb = __float2bfloat16(v);
                        ((bf16*)out0)[row * N + col] = hb;
                        ((bf16*)out1)[row * N + col] =
                            __float2bfloat16(v - __bfloat162float(hb));
                    }
                }
    }
}

// ---------------------------------------------------------------------------
// s + softmax + mask: block = (32 q-rows, batch); 512 thr = 8 waves
// wave = (wr 0..1 row-tile, wq 0..3 col-quarter). k hi/lo staged in LDS.
// beta -> fp32 d_out and bf16 ws (for PV GEMM).
// ---------------------------------------------------------------------------
__global__ __launch_bounds__(512) void attn_s(
    const bf16* __restrict__ qh, const bf16* __restrict__ ql,
    const bf16* __restrict__ kh, const bf16* __restrict__ kl,
    const float* __restrict__ masks, float* __restrict__ beta_out,
    bf16* __restrict__ betaB) {
    __shared__ bf16 kH[256 * 32], kL[256 * 32];
    __shared__ float redM[4][32], redS[4][32];
    const int b = blockIdx.y, qt = blockIdx.x;
    const int tid = threadIdx.x, wave = tid >> 6, lane = tid & 63;
    const int quad = lane >> 4, l15 = lane & 15;
    const int wr = wave >> 2, wq = wave & 3;

    f32x4 acc[4] = {};
    const size_t qoff = ((size_t)(b * 256 + qt * 32 + wr * 16 + l15)) * 512;
    const size_t kbase = (size_t)(b * 256) * 512;

    for (int k0 = 0; k0 < 512; k0 += 32) {
        stage_async_256_w8(kh + kbase + k0, 512, kH, wave, lane);
        stage_async_256_w8(kl + kbase + k0, 512, kL, wave, lane);
        __syncthreads();
        const short8 aH = *(const short8*)(qh + qoff + k0 + quad * 8);
        const short8 aL = *(const short8*)(ql + qoff + k0 + quad * 8);
#pragma unroll
        for (int nt = 0; nt < 4; ++nt) {
            const int kr = wq * 64 + nt * 16 + l15;
            const short8 bH = *(const short8*)(&kH[kr * 32 + quad * 8]);
            const short8 bL = *(const short8*)(&kL[kr * 32 + quad * 8]);
            acc[nt] = MFMA_BF16(aH, bH, acc[nt]);
            acc[nt] = MFMA_BF16(aH, bL, acc[nt]);
            acc[nt] = MFMA_BF16(aL, bH, acc[nt]);
        }
        __syncthreads();
    }

    // per-wave partial softmax over its 64 cols
    float pm[4], ps[4];
#pragma unroll
    for (int i = 0; i < 4; ++i) {
        float m = fmaxf(fmaxf(acc[0][i], acc[1][i]), fmaxf(acc[2][i], acc[3][i]));
#pragma unroll
        for (int s = 1; s < 16; s <<= 1) m = fmaxf(m, __shfl_xor(m, s));
        float sum = 0.f;
#pragma unroll
        for (int nt = 0; nt < 4; ++nt) sum += __expf(acc[nt][i] - m);
#pragma unroll
        for (int s = 1; s < 16; s <<= 1) sum += __shfl_xor(sum, s);
        pm[i] = m;
        ps[i] = sum;
    }
    if (l15 == 0) {
#pragma unroll
        for (int i = 0; i < 4; ++i) {
            redM[wq][wr * 16 + quad * 4 + i] = pm[i];
            redS[wq][wr * 16 + quad * 4 + i] = ps[i];
        }
    }
    __syncthreads();
    float gm[4], ginv[4];
#pragma unroll
    for (int i = 0; i < 4; ++i) {
        const int r = wr * 16 + quad * 4 + i;
        const float m = fmaxf(fmaxf(redM[0][r], redM[1][r]), fmaxf(redM[2][r], redM[3][r]));
        const float s = redS[0][r] * __expf(redM[0][r] - m) +
                        redS[1][r] * __expf(redM[1][r] - m) +
                        redS[2][r] * __expf(redM[2][r] - m) +
                        redS[3][r] * __expf(redM[3][r] - m);
        gm[i] = m;
        ginv[i] = 1.0f / s;
    }
#pragma unroll
    for (int nt = 0; nt < 4; ++nt) {
        const int col = wq * 64 + nt * 16 + l15;
        const float mv = masks[b * 256 + col];
#pragma unroll
        for (int i = 0; i < 4; ++i) {
            const int row = qt * 32 + wr * 16 + quad * 4 + i;
            const float bvv = __expf(acc[nt][i] - gm[i]) * ginv[i] * mv;
            const size_t idx = ((size_t)(b * 256 + row)) * 256 + col;
            beta_out[idx] = bvv;
            betaB[idx] = __float2bfloat16(bvv);
        }
    }
}

// ---------------------------------------------------------------------------
extern "C" void kernel_launch(void* const* d_in, const int* in_sizes, int n_in,
                              void* d_out, int out_size, void* d_ws, size_t ws_size,
                              hipStream_t stream) {
    const float* x1 = (const float*)d_in[0];
    const float* x2 = (const float*)d_in[1];
    const float* masks = (const float*)d_in[2];
    const float* Wq = (const float*)d_in[3];
    const float* bq = (const float*)d_in[4];
    const float* Wk = (const float*)d_in[5];
    const float* bk = (const float*)d_in[6];
    const float* Wv = (const float*)d_in[7];
    const float* bv = (const float*)d_in[8];
    const float* Wo = (const float*)d_in[9];
    const float* bo = (const float*)d_in[10];

    char* ws = (char*)d_ws;
    bf16* WqTh = (bf16*)(ws + 0);            // 512x1024
    bf16* WqTl = (bf16*)(ws + 1048576);
    bf16* WkTh = (bf16*)(ws + 2097152);      // 512x768
    bf16* WkTl = (bf16*)(ws + 2883584);
    bf16* WvTh = (bf16*)(ws + 3670016);      // 1024x768
    bf16* WoTh = (bf16*)(ws + 5242880);      // 1024x1024
    bf16* qh = (bf16*)(ws + 7340032);        // 16384x512
    bf16* ql = (bf16*)(ws + 24117248);
    bf16* kh = (bf16*)(ws + 40894464);
    bf16* kl = (bf16*)(ws + 57671680);
    bf16* vT = (bf16*)(ws + 74448896);       // [b][ch][tok] 16384x1024... 33.5MB
    bf16* betaB = (bf16*)(ws + 108003328);   // 16384x256
    bf16* o_mid = (bf16*)(ws + 7340032);     // overlays qh/ql (dead after attn_s)
    // total ws use: 116,391,936 bytes

    float* out_o = (float*)d_out;
    float* out_beta = out_o + (size_t)16384 * 1024;

    const dim3 tb(32, 8);
    transpose_split<true><<<dim3(16, 32), tb, 0, stream>>>(Wq, WqTh, WqTl, 1024, 512);
    transpose_split<true><<<dim3(16, 24), tb, 0, stream>>>(Wk, WkTh, WkTl, 768, 512);
    transpose_split<false><<<dim3(32, 24), tb, 0, stream>>>(Wv, WvTh, nullptr, 768, 1024);
    transpose_split<false><<<dim3(32, 32), tb, 0, stream>>>(Wo, WoTh, nullptr, 1024, 1024);

    // q = x1@Wq + bq -> hi/lo ; k = x2@Wk + bk -> hi/lo
    gemm2<G_SPLIT3><<<dim3(4, 128), 256, 0, stream>>>(x1, WqTh, WqTl, bq, qh, ql, 512, 1024);
    gemm2<G_SPLIT3><<<dim3(4, 128), 256, 0, stream>>>(x2, WkTh, WkTl, bk, kh, kl, 512, 768);
    // v = x2@Wv + bv -> vT[b][ch][tok]
    gemm2<G_VT><<<dim3(8, 128), 256, 0, stream>>>(x2, WvTh, nullptr, bv, vT, nullptr, 1024, 768);

    // s = q@k^T, softmax, mask -> beta (fp32 out + bf16 ws)
    attn_s<<<dim3(8, 64), 512, 0, stream>>>(qh, ql, kh, kl, masks, out_beta, betaB);

    // o_mid = beta @ v (batched)
    gemm2<G_PV><<<dim3(8, 2, 64), 256, 0, stream>>>(betaB, vT, nullptr, nullptr, o_mid,
                                                    nullptr, 1024, 256);
    // out = o_mid@Wo + bo (fp32)
    gemm2<G_F32><<<dim3(8, 128), 256, 0, stream>>>(o_mid, WoTh, nullptr, bo, out_o,
                                                   nullptr, 1024, 1024);
}

// Round 5
// 470.381 us; speedup vs baseline: 1.2509x; 1.0843x over previous
//
#include <hip/hip_runtime.h>
#include <hip/hip_bf16.h>

using bf16 = __hip_bfloat16;

typedef __attribute__((ext_vector_type(8))) short short8;   // 8 bf16 = 16B
typedef __attribute__((ext_vector_type(4))) short shortx4;  // 4 bf16 = 8B
typedef __attribute__((ext_vector_type(4))) float f32x4;    // 16B

#define MFMA_BF16(a, b, c) __builtin_amdgcn_mfma_f32_16x16x32_bf16((a), (b), (c), 0, 0, 0)

// async global->LDS, 16B per lane; LDS dest = wave-uniform base + lane*16
__device__ __forceinline__ void lds_load16(const void* g, void* l) {
    __builtin_amdgcn_global_load_lds(
        (const __attribute__((address_space(1))) void*)g,
        (__attribute__((address_space(3))) void*)l, 16, 0, 0);
}

// XCD-aware block swizzle: flat%8 ~ XCD id. Map so each XCD owns a contiguous
// band of by-rows (A-tile fetched on exactly one XCD; 8 consecutive same-XCD
// blocks share one A row-tile). Requires gridDim.y % 8 == 0.
__device__ __forceinline__ void swiz_xcd(int& bx, int& by) {
    const int NX = gridDim.x, NY = gridDim.y;
    const int flat = blockIdx.y * NX + blockIdx.x;
    const int cid = flat & 7, slot = flat >> 3;
    by = cid * (NY >> 3) + slot / NX;
    bx = slot % NX;
}

// stage 128x32 bf16 tile (row-major src, ld elems) -> LDS stride 32, 256-thr block
__device__ __forceinline__ void stage_async_128(const bf16* src, int ld, bf16* tile,
                                                int wave, int lane) {
    const int r = lane >> 2, c = (lane & 3) * 8;
#pragma unroll
    for (int p = 0; p < 2; ++p) {
        const int row = p * 64 + wave * 16;
        lds_load16(src + (size_t)(row + r) * ld + c, tile + row * 32);
    }
}
// stage 256x32 bf16 tile with 512-thr block (8 waves)
__device__ __forceinline__ void stage_async_256_w8(const bf16* src, int ld, bf16* tile,
                                                   int wave, int lane) {
    const int r = lane >> 2, c = (lane & 3) * 8;
#pragma unroll
    for (int p = 0; p < 2; ++p) {
        const int row = p * 128 + wave * 16;
        lds_load16(src + (size_t)(row + r) * ld + c, tile + row * 32);
    }
}
// stage 128x32 fp32 tile with hi(/lo) bf16 conversion -> LDS stride 40
template <bool SPLIT>
__device__ __forceinline__ void stage_conv_128(const float* src, int ld, bf16* th,
                                               bf16* tl, int tid) {
#pragma unroll
    for (int it = 0; it < 4; ++it) {
        const int vid = tid + 256 * it;
        const int row = vid >> 3, col = (vid & 7) * 4;
        const f32x4 x = *(const f32x4*)(src + (size_t)row * ld + col);
        shortx4 h, l;
#pragma unroll
        for (int j = 0; j < 4; ++j) {
            bf16 hb = __float2bfloat16(x[j]);
            h[j] = *(short*)&hb;
            if constexpr (SPLIT) {
                bf16 lb = __float2bfloat16(x[j] - __bfloat162float(hb));
                l[j] = *(short*)&lb;
            }
        }
        *(shortx4*)(&th[row * 40 + col]) = h;
        if constexpr (SPLIT) *(shortx4*)(&tl[row * 40 + col]) = l;
    }
}

// ---------------------------------------------------------------------------
// Weight transpose fp32 in[K][N] -> bf16 hi(/lo) out[N][K]
// ---------------------------------------------------------------------------
template <bool SPLIT>
__global__ void transpose_split(const float* __restrict__ in, bf16* __restrict__ outh,
                                bf16* __restrict__ outl, int K, int N) {
    __shared__ float t[32][33];
    const int n0 = blockIdx.x * 32, k0 = blockIdx.y * 32;
    const int tx = threadIdx.x, ty = threadIdx.y;  // (32, 8)
#pragma unroll
    for (int i = 0; i < 4; ++i)
        t[ty + i * 8][tx] = in[(size_t)(k0 + ty + i * 8) * N + n0 + tx];
    __syncthreads();
#pragma unroll
    for (int i = 0; i < 4; ++i) {
        const float x = t[tx][ty + i * 8];
        const bf16 hb = __float2bfloat16(x);
        const size_t idx = (size_t)(n0 + ty + i * 8) * K + k0 + tx;
        outh[idx] = hb;
        if constexpr (SPLIT) outl[idx] = __float2bfloat16(x - __bfloat162float(hb));
    }
}

// ---------------------------------------------------------------------------
// Unified 128x128x32 MFMA GEMM, C = A @ Bt^T (+bias). 4 waves, 4x4 tiles/wave.
//  G_SPLIT3: A fp32 (conv hi/lo), B bf16 hi/lo async; 3-MFMA; out hi/lo bf16.
//  G_VT    : A fp32 (conv hi), B bf16 async; out bf16 transposed per batch.
//  G_F32   : A bf16 async, B bf16 async; out fp32 + bias.
//  G_PV    : batched (z): A bf16 async, B bf16 async; out bf16, no bias.
// LDS: one carved buffer; G_VT's Ts epilogue aliases dead staging tiles.
// ---------------------------------------------------------------------------
enum { G_SPLIT3 = 0, G_VT = 1, G_F32 = 2, G_PV = 3 };

template <int MODE>
__global__ __launch_bounds__(256) void gemm2(
    const void* __restrict__ Av, const bf16* __restrict__ Bth,
    const bf16* __restrict__ Btl, const float* __restrict__ bias,
    void* __restrict__ out0, void* __restrict__ out1, int N, int K) {
    constexpr bool ASPLIT = (MODE == G_SPLIT3);
    constexpr bool ACONV = (MODE == G_SPLIT3 || MODE == G_VT);
    constexpr int LDA = ACONV ? 40 : 32;
    constexpr int SZ_A = 128 * LDA * 2;
    constexpr int SZ_AL = ASPLIT ? 128 * 40 * 2 : 0;
    constexpr int SZ_B = 128 * 32 * 2;
    constexpr int STAGE = SZ_A + SZ_AL + SZ_B + (ASPLIT ? SZ_B : 0);
    constexpr int SMEM =
        (MODE == G_VT) ? (STAGE > 128 * 136 * 2 ? STAGE : 128 * 136 * 2) : STAGE;
    __shared__ __align__(16) char smem[SMEM];
    bf16* AsH = (bf16*)smem;
    bf16* AsL = (bf16*)(smem + SZ_A);
    bf16* BsH = (bf16*)(smem + SZ_A + SZ_AL);
    bf16* BsL = (bf16*)(smem + SZ_A + SZ_AL + SZ_B);
    bf16* Ts = (bf16*)smem;  // G_VT epilogue only (staging dead by then)

    const int tid = threadIdx.x, wave = tid >> 6, lane = tid & 63;
    const int quad = lane >> 4, l15 = lane & 15;
    const int wr = wave >> 1, wc = wave & 1;

    int bx, by;
    if constexpr (MODE == G_PV) {
        bx = blockIdx.x;
        by = blockIdx.y;
    } else {
        swiz_xcd(bx, by);
    }
    const int m0 = by * 128, n0 = bx * 128;
    const int z = blockIdx.z;

    const float* Af = (const float*)Av;
    const bf16* Ab = (const bf16*)Av;
    const bf16* Bh = Bth;
    if constexpr (MODE == G_PV) {
        Ab += (size_t)z * 256 * 256;   // beta batch
        Bh += (size_t)z * 1024 * 256;  // vT batch
    }

    f32x4 acc[4][4] = {};
    for (int k0 = 0; k0 < K; k0 += 32) {
        if constexpr (ACONV)
            stage_conv_128<ASPLIT>(Af + (size_t)m0 * K + k0, K, AsH, AsL, tid);
        else
            stage_async_128(Ab + (size_t)m0 * K + k0, K, AsH, wave, lane);
        stage_async_128(Bh + (size_t)n0 * K + k0, K, BsH, wave, lane);
        if constexpr (ASPLIT)
            stage_async_128(Btl + (size_t)n0 * K + k0, K, BsL, wave, lane);
        __syncthreads();

        short8 ah[4], bh[4];
#pragma unroll
        for (int t = 0; t < 4; ++t) {
            ah[t] = *(const short8*)(&AsH[(wr * 64 + t * 16 + l15) * LDA + quad * 8]);
            bh[t] = *(const short8*)(&BsH[(wc * 64 + t * 16 + l15) * 32 + quad * 8]);
        }
        if constexpr (ASPLIT) {
            short8 al[4], bl[4];
#pragma unroll
            for (int t = 0; t < 4; ++t) {
                al[t] = *(const short8*)(&AsL[(wr * 64 + t * 16 + l15) * 40 + quad * 8]);
                bl[t] = *(const short8*)(&BsL[(wc * 64 + t * 16 + l15) * 32 + quad * 8]);
            }
#pragma unroll
            for (int ti = 0; ti < 4; ++ti)
#pragma unroll
                for (int tj = 0; tj < 4; ++tj) {
                    acc[ti][tj] = MFMA_BF16(al[ti], bh[tj], acc[ti][tj]);
                    acc[ti][tj] = MFMA_BF16(ah[ti], bl[tj], acc[ti][tj]);
                    acc[ti][tj] = MFMA_BF16(ah[ti], bh[tj], acc[ti][tj]);
                }
        } else {
#pragma unroll
            for (int ti = 0; ti < 4; ++ti)
#pragma unroll
                for (int tj = 0; tj < 4; ++tj)
                    acc[ti][tj] = MFMA_BF16(ah[ti], bh[tj], acc[ti][tj]);
        }
        __syncthreads();
    }

    float bv4[4] = {0.f, 0.f, 0.f, 0.f};
    if constexpr (MODE != G_PV) {
#pragma unroll
        for (int tj = 0; tj < 4; ++tj) bv4[tj] = bias[n0 + wc * 64 + tj * 16 + l15];
    }

    if constexpr (MODE == G_VT) {
#pragma unroll
        for (int ti = 0; ti < 4; ++ti)
#pragma unroll
            for (int tj = 0; tj < 4; ++tj)
#pragma unroll
                for (int i = 0; i < 4; ++i) {
                    const int ml = wr * 64 + ti * 16 + quad * 4 + i;
                    const int nl = wc * 64 + tj * 16 + l15;
                    Ts[nl * 136 + ml] = __float2bfloat16(acc[ti][tj][i] + bv4[tj]);
                }
        __syncthreads();
        const int bIdx = m0 >> 8, tok0 = m0 & 255;
        const int nl = tid >> 1, half = tid & 1;
        bf16* dst = (bf16*)out0 + ((size_t)bIdx * N + n0 + nl) * 256 + tok0 + half * 64;
        const bf16* src = &Ts[nl * 136 + half * 64];
#pragma unroll
        for (int j = 0; j < 8; ++j)
            *(short8*)(dst + j * 8) = *(const short8*)(src + j * 8);
    } else {
#pragma unroll
        for (int ti = 0; ti < 4; ++ti)
#pragma unroll
            for (int tj = 0; tj < 4; ++tj)
#pragma unroll
                for (int i = 0; i < 4; ++i) {
                    const size_t row = m0 + wr * 64 + ti * 16 + quad * 4 + i;
                    const size_t col = n0 + wc * 64 + tj * 16 + l15;
                    const float v = acc[ti][tj][i] + bv4[tj];
                    if constexpr (MODE == G_F32) {
                        ((float*)out0)[row * N + col] = v;
                    } else if constexpr (MODE == G_PV) {
                        ((bf16*)out0)[((size_t)z * 256 + row) * N + col] =
                            __float2bfloat16(v);
                    } else {  // G_SPLIT3: hi/lo outputs
                        const bf16 hb = __float2bfloat16(v);
                        ((bf16*)out0)[row * N + col] = hb;
                        ((bf16*)out1)[row * N + col] =
                            __float2bfloat16(v - __bfloat162float(hb));
                    }
                }
    }
}

// ---------------------------------------------------------------------------
// s + softmax + mask: block = (32 q-rows, batch); 512 thr = 8 waves
// wave = (wr 0..1 row-tile, wq 0..3 col-quarter). k hi/lo staged in LDS.
// beta -> fp32 d_out and bf16 ws (for PV GEMM). XCD swizzle over (qt, b).
// ---------------------------------------------------------------------------
__global__ __launch_bounds__(512) void attn_s(
    const bf16* __restrict__ qh, const bf16* __restrict__ ql,
    const bf16* __restrict__ kh, const bf16* __restrict__ kl,
    const float* __restrict__ masks, float* __restrict__ beta_out,
    bf16* __restrict__ betaB) {
    __shared__ bf16 kH[256 * 32], kL[256 * 32];
    __shared__ float redM[4][32], redS[4][32];
    int qt, b;
    swiz_xcd(qt, b);  // grid (8, 64): each XCD owns 8 batches; k fetched once
    const int tid = threadIdx.x, wave = tid >> 6, lane = tid & 63;
    const int quad = lane >> 4, l15 = lane & 15;
    const int wr = wave >> 2, wq = wave & 3;

    f32x4 acc[4] = {};
    const size_t qoff = ((size_t)(b * 256 + qt * 32 + wr * 16 + l15)) * 512;
    const size_t kbase = (size_t)(b * 256) * 512;

    for (int k0 = 0; k0 < 512; k0 += 32) {
        stage_async_256_w8(kh + kbase + k0, 512, kH, wave, lane);
        stage_async_256_w8(kl + kbase + k0, 512, kL, wave, lane);
        __syncthreads();
        const short8 aH = *(const short8*)(qh + qoff + k0 + quad * 8);
        const short8 aL = *(const short8*)(ql + qoff + k0 + quad * 8);
#pragma unroll
        for (int nt = 0; nt < 4; ++nt) {
            const int kr = wq * 64 + nt * 16 + l15;
            const short8 bH = *(const short8*)(&kH[kr * 32 + quad * 8]);
            const short8 bL = *(const short8*)(&kL[kr * 32 + quad * 8]);
            acc[nt] = MFMA_BF16(aH, bH, acc[nt]);
            acc[nt] = MFMA_BF16(aH, bL, acc[nt]);
            acc[nt] = MFMA_BF16(aL, bH, acc[nt]);
        }
        __syncthreads();
    }

    // per-wave partial softmax over its 64 cols
    float pm[4], ps[4];
#pragma unroll
    for (int i = 0; i < 4; ++i) {
        float m = fmaxf(fmaxf(acc[0][i], acc[1][i]), fmaxf(acc[2][i], acc[3][i]));
#pragma unroll
        for (int s = 1; s < 16; s <<= 1) m = fmaxf(m, __shfl_xor(m, s));
        float sum = 0.f;
#pragma unroll
        for (int nt = 0; nt < 4; ++nt) sum += __expf(acc[nt][i] - m);
#pragma unroll
        for (int s = 1; s < 16; s <<= 1) sum += __shfl_xor(sum, s);
        pm[i] = m;
        ps[i] = sum;
    }
    if (l15 == 0) {
#pragma unroll
        for (int i = 0; i < 4; ++i) {
            redM[wq][wr * 16 + quad * 4 + i] = pm[i];
            redS[wq][wr * 16 + quad * 4 + i] = ps[i];
        }
    }
    __syncthreads();
    float gm[4], ginv[4];
#pragma unroll
    for (int i = 0; i < 4; ++i) {
        const int r = wr * 16 + quad * 4 + i;
        const float m = fmaxf(fmaxf(redM[0][r], redM[1][r]), fmaxf(redM[2][r], redM[3][r]));
        const float s = redS[0][r] * __expf(redM[0][r] - m) +
                        redS[1][r] * __expf(redM[1][r] - m) +
                        redS[2][r] * __expf(redM[2][r] - m) +
                        redS[3][r] * __expf(redM[3][r] - m);
        gm[i] = m;
        ginv[i] = 1.0f / s;
    }
#pragma unroll
    for (int nt = 0; nt < 4; ++nt) {
        const int col = wq * 64 + nt * 16 + l15;
        const float mv = masks[b * 256 + col];
#pragma unroll
        for (int i = 0; i < 4; ++i) {
            const int row = qt * 32 + wr * 16 + quad * 4 + i;
            const float bvv = __expf(acc[nt][i] - gm[i]) * ginv[i] * mv;
            const size_t idx = ((size_t)(b * 256 + row)) * 256 + col;
            beta_out[idx] = bvv;
            betaB[idx] = __float2bfloat16(bvv);
        }
    }
}

// ---------------------------------------------------------------------------
extern "C" void kernel_launch(void* const* d_in, const int* in_sizes, int n_in,
                              void* d_out, int out_size, void* d_ws, size_t ws_size,
                              hipStream_t stream) {
    const float* x1 = (const float*)d_in[0];
    const float* x2 = (const float*)d_in[1];
    const float* masks = (const float*)d_in[2];
    const float* Wq = (const float*)d_in[3];
    const float* bq = (const float*)d_in[4];
    const float* Wk = (const float*)d_in[5];
    const float* bk = (const float*)d_in[6];
    const float* Wv = (const float*)d_in[7];
    const float* bv = (const float*)d_in[8];
    const float* Wo = (const float*)d_in[9];
    const float* bo = (const float*)d_in[10];

    char* ws = (char*)d_ws;
    bf16* WqTh = (bf16*)(ws + 0);            // 512x1024
    bf16* WqTl = (bf16*)(ws + 1048576);
    bf16* WkTh = (bf16*)(ws + 2097152);      // 512x768
    bf16* WkTl = (bf16*)(ws + 2883584);
    bf16* WvTh = (bf16*)(ws + 3670016);      // 1024x768
    bf16* WoTh = (bf16*)(ws + 5242880);      // 1024x1024
    bf16* qh = (bf16*)(ws + 7340032);        // 16384x512
    bf16* ql = (bf16*)(ws + 24117248);
    bf16* kh = (bf16*)(ws + 40894464);
    bf16* kl = (bf16*)(ws + 57671680);
    bf16* vT = (bf16*)(ws + 74448896);       // [b][ch][tok] bf16
    bf16* betaB = (bf16*)(ws + 108003328);   // 16384x256
    bf16* o_mid = (bf16*)(ws + 7340032);     // overlays qh/ql (dead after attn_s)
    // total ws use: 116,391,936 bytes

    float* out_o = (float*)d_out;
    float* out_beta = out_o + (size_t)16384 * 1024;

    const dim3 tb(32, 8);
    transpose_split<true><<<dim3(16, 32), tb, 0, stream>>>(Wq, WqTh, WqTl, 1024, 512);
    transpose_split<true><<<dim3(16, 24), tb, 0, stream>>>(Wk, WkTh, WkTl, 768, 512);
    transpose_split<false><<<dim3(32, 24), tb, 0, stream>>>(Wv, WvTh, nullptr, 768, 1024);
    transpose_split<false><<<dim3(32, 32), tb, 0, stream>>>(Wo, WoTh, nullptr, 1024, 1024);

    // q = x1@Wq + bq -> hi/lo ; k = x2@Wk + bk -> hi/lo
    gemm2<G_SPLIT3><<<dim3(4, 128), 256, 0, stream>>>(x1, WqTh, WqTl, bq, qh, ql, 512, 1024);
    gemm2<G_SPLIT3><<<dim3(4, 128), 256, 0, stream>>>(x2, WkTh, WkTl, bk, kh, kl, 512, 768);
    // v = x2@Wv + bv -> vT[b][ch][tok]
    gemm2<G_VT><<<dim3(8, 128), 256, 0, stream>>>(x2, WvTh, nullptr, bv, vT, nullptr, 1024, 768);

    // s = q@k^T, softmax, mask -> beta (fp32 out + bf16 ws)
    attn_s<<<dim3(8, 64), 512, 0, stream>>>(qh, ql, kh, kl, masks, out_beta, betaB);

    // o_mid = beta @ v (batched)
    gemm2<G_PV><<<dim3(8, 2, 64), 256, 0, stream>>>(betaB, vT, nullptr, nullptr, o_mid,
                                                    nullptr, 1024, 256);
    // out = o_mid@Wo + bo (fp32)
    gemm2<G_F32><<<dim3(8, 128), 256, 0, stream>>>(o_mid, WoTh, nullptr, bo, out_o,
                                                   nullptr, 1024, 1024);
}